// Round 1
// baseline (298.538 us; speedup 1.0000x reference)
//
#include <hip/hip_runtime.h>

#define B_ 4
#define N_ 8192
#define DIN 64
#define HDIM 64
#define DOUT 128
#define KNN 16
#define QPB 64               // queries per block (= lanes per wave)
#define PART 8               // partner waves per query block
#define NTHR (QPB * PART)    // 512 threads / block
#define CHUNK (N_ / PART)    // 1024 candidates per thread
#define CAP 24               // deferred-insert buffer slots per thread
#define UNR 16               // candidates per scan iteration (loads in flight)
#define BLOCKS_PER_B (N_ / QPB)  // 128
#define GMARGIN 1e-3f        // conservative slack for the g<G fast filter

// ---------------- K_prep: pack (x,y,z,sq) + compose affine params ----------------
__global__ __launch_bounds__(256) void k_prep(
    const float* __restrict__ xyz,
    const float* __restrict__ w1, const float* __restrict__ b1,
    const float* __restrict__ w2, const float* __restrict__ b2,
    const float* __restrict__ w3, const float* __restrict__ b3,
    float4* __restrict__ pk, float4* __restrict__ prm) {
  const int blk = blockIdx.x, t = threadIdx.x;
  const int b = blk >> 5;
  const int m = ((blk & 31) << 8) + t;
  const float* xb = xyz + (size_t)b * 3 * N_;
  float x = xb[m], y = xb[N_ + m], z = xb[2 * N_ + m];
  float sq = __fadd_rn(__fadd_rn(__fmul_rn(x, x), __fmul_rn(y, y)), __fmul_rn(z, z));
  pk[((size_t)b << 13) + m] = make_float4(x, y, z, sq);

  if (blk == 0) {
    __shared__ float M2[HDIM][10];
    __shared__ float bb[HDIM];
    const int o = t;
    if (o < HDIM) {
      float r[10];
#pragma unroll
      for (int c = 0; c < 10; c++) r[c] = 0.f;
      float s = b2[o];
      for (int l = 0; l < HDIM; l++) {
        float w = w2[o * HDIM + l];
#pragma unroll
        for (int c = 0; c < 10; c++) r[c] = fmaf(w, w1[l * 10 + c], r[c]);
        s = fmaf(w, b1[l], s);
      }
#pragma unroll
      for (int c = 0; c < 10; c++) M2[o][c] = r[c];
      bb[o] = s;
    }
    __syncthreads();
    if (o < HDIM) {
      float r3[10];
#pragma unroll
      for (int c = 0; c < 10; c++) r3[c] = 0.f;
      float bc = b3[o];
      for (int l = 0; l < HDIM; l++) {
        float w = w3[o * HDIM + l];
#pragma unroll
        for (int c = 0; c < 10; c++) r3[c] = fmaf(w, M2[l][c], r3[c]);
        bc = fmaf(w, bb[l], bc);
      }
      prm[o]      = make_float4(r3[0] - r3[6], r3[1] - r3[7], r3[2] - r3[8], bc);
      prm[64 + o] = make_float4(r3[3] + r3[6], r3[4] + r3[7], r3[5] + r3[8], r3[9]);
    }
  }
}

// replace-max insert into unsorted top-16 kept in registers (fully unrolled)
#define INSERT16(VARR, IARR, VMAX, DVAL, MIDX)                    \
  {                                                               \
    bool done = false;                                            \
    _Pragma("unroll") for (int _i = 0; _i < KNN; _i++) {          \
      bool hit = (!done) && (VARR[_i] == VMAX);                   \
      if (hit) { VARR[_i] = (DVAL); IARR[_i] = (MIDX); }          \
      done = done | hit;                                          \
    }                                                             \
    float _a = fmaxf(fmaxf(fmaxf(VARR[0], VARR[1]), fmaxf(VARR[2], VARR[3])),   \
                     fmaxf(fmaxf(VARR[4], VARR[5]), fmaxf(VARR[6], VARR[7])));  \
    float _b = fmaxf(fmaxf(fmaxf(VARR[8], VARR[9]), fmaxf(VARR[10], VARR[11])), \
                     fmaxf(fmaxf(VARR[12], VARR[13]), fmaxf(VARR[14], VARR[15])));\
    VMAX = fmaxf(_a, _b);                                         \
  }

#define MAX16(VARR, VMAX)                                         \
  {                                                               \
    float _a = fmaxf(fmaxf(fmaxf(VARR[0], VARR[1]), fmaxf(VARR[2], VARR[3])),   \
                     fmaxf(fmaxf(VARR[4], VARR[5]), fmaxf(VARR[6], VARR[7])));  \
    float _b = fmaxf(fmaxf(fmaxf(VARR[8], VARR[9]), fmaxf(VARR[10], VARR[11])), \
                     fmaxf(fmaxf(VARR[12], VARR[13]), fmaxf(VARR[14], VARR[15])));\
    VMAX = fmaxf(_a, _b);                                         \
  }

// drain deferred buffer through INSERT16, publish tau, tighten gate
#define FLUSH()                                                   \
  {                                                               \
    for (int c_ = 0; c_ < cnt; c_++) {                            \
      float fd_ = poolF[c_ * NTHR + t];                           \
      int fm_ = poolI[c_ * NTHR + t];                             \
      if (fd_ < vmax) { INSERT16(v, id, vmax, fd_, fm_); }        \
    }                                                             \
    cnt = 0;                                                      \
    atomicMin(&tau[q], __float_as_uint(vmax));                    \
    gate = fminf(vmax, __uint_as_float(tau[q]));                  \
  }

// ---------------- K1: fused kNN + fe + shortcut + output ----------------
// block: 64 queries x 8 partner waves; wave j scans candidates [j*1024,(j+1)*1024)
// Scan loads are forced onto the VECTOR path (opaque VGPR offset) so 16
// global_load_dwordx4 stay in flight under vmcnt graduated waits, instead of
// s_load batches serialized by lgkmcnt(0). Fast filter: g<G (3 fma + cmp),
// conservative by GMARGIN; exact reference-rounded d recomputed only on push.
// Tail: tree-merge top-16, gather, fe (composed affine + maxpool), shortcut GEMM.
__global__ __launch_bounds__(NTHR, 4) void k_knn_fe(
    const float4* __restrict__ pk, const float4* __restrict__ prm,
    const float* __restrict__ feature, const float* __restrict__ wsM,
    const float* __restrict__ bs, float* __restrict__ out) {
  const int blk = blockIdx.x;
  const int b  = blk / BLOCKS_PER_B;
  const int n0 = (blk % BLOCKS_PER_B) * QPB;
  const int t = threadIdx.x;
  const int q = t & 63;
  const int j = __builtin_amdgcn_readfirstlane(t >> 6);  // wave-uniform partner id

  __shared__ unsigned tau[QPB];
  __shared__ float4 prmL[2 * HDIM];
  // 72 KB pool, time-multiplexed:
  //  scan:   poolF[c*512+t] (48KB), poolI[c*512+t] (24KB)      (c < CAP)
  //  merge:  rows r<128: poolF[r*64+q], poolI[r*64+q]
  //  gather: rows r<64 of poolF = neighbor x/y/z/dsq
  //  epilogue: poolF = ws[128][64], poolI-as-float = feature tile [64][64]
  __shared__ alignas(16) float poolF[CAP * NTHR];
  __shared__ alignas(16) unsigned short poolI[CAP * NTHR];

  if (t < QPB) tau[t] = 0x7f800000u;  // +inf
  for (int i = t; i < 2 * HDIM; i += NTHR) prmL[i] = prm[i];

  const float4 qv = pk[((size_t)b << 13) + n0 + q];
  const float qx = qv.x, qy = qv.y, qz = qv.z, qs = qv.w;
  const float nx2 = -2.0f * qx, ny2 = -2.0f * qy, nz2 = -2.0f * qz;

  const float INF = __uint_as_float(0x7f800000u);
  float v[KNN]; int id[KNN];
  float vmax, gate;
  int cnt = 0;
  __syncthreads();

  const float4* pj = pk + ((size_t)b << 13) + j * CHUNK;

  // warm start: first 16 candidates fill the list directly (no gating, no flush
  // storm; list order = scan order so tie semantics match the gated path)
  {
    float4 c[KNN];
#pragma unroll
    for (int e = 0; e < KNN; e++) c[e] = pj[e];
#pragma unroll
    for (int e = 0; e < KNN; e++) {
      float dot = fmaf(c[e].z, qz, fmaf(c[e].y, qy, __fmul_rn(c[e].x, qx)));
      v[e] = __fsub_rn(__fadd_rn(qs, c[e].w), __fmul_rn(2.0f, dot));
      id[e] = j * CHUNK + e;
    }
    MAX16(v, vmax);
    atomicMin(&tau[q], __float_as_uint(vmax));   // publish early so partners gate
    gate = fminf(vmax, __uint_as_float(tau[q]));
  }

  // opaque zero in a VGPR: defeats uniformity analysis so candidate loads go
  // down the vector path (global_load_dwordx4, vmcnt pipelining), not s_load.
  int voff = 0;
  asm volatile("" : "+v"(voff));
  const float4* pjv = pj + voff;

  unsigned tnext = tau[q];  // software-pipelined gate refresh
  for (int u0 = KNN; u0 < CHUNK; u0 += UNR) {
    if (__any(cnt > CAP - UNR)) { FLUSH(); }
    float4 c[UNR];
#pragma unroll
    for (int e = 0; e < UNR; e++) c[e] = pjv[u0 + e];  // 16 loads in flight
    gate = fminf(gate, __uint_as_float(tnext));  // partners' progress (1 iter stale)
    tnext = tau[q];                              // issue now, consume next iter
    float G = __fadd_rn(__fsub_rn(gate, qs), GMARGIN);
#pragma unroll
    for (int e = 0; e < UNR; e++) {
      // fast filter: g = cw - 2*dot (fused); strict superset of d<gate by GMARGIN
      float g = fmaf(c[e].x, nx2, fmaf(c[e].y, ny2, fmaf(c[e].z, nz2, c[e].w)));
      if (g < G) {
        // exact reference rounding only on the rare push; FLUSH re-filters exactly
        float dot = fmaf(c[e].z, qz, fmaf(c[e].y, qy, __fmul_rn(c[e].x, qx)));
        float d = __fsub_rn(__fadd_rn(qs, c[e].w), __fmul_rn(2.0f, dot));
        poolF[cnt * NTHR + t] = d;
        poolI[cnt * NTHR + t] = (unsigned short)(j * CHUNK + u0 + e);
        cnt++;
      }
    }
  }
  FLUSH();
  __syncthreads();

  // publish per-thread lists: rows j*16+i (ascending-m order across j)
#pragma unroll
  for (int i = 0; i < KNN; i++) {
    poolF[(j * KNN + i) * QPB + q] = v[i];
    poolI[(j * KNN + i) * QPB + q] = (unsigned short)id[i];
  }
  __syncthreads();

  float fv[KNN]; int fid[KNN]; float fm = INF;
  // stage A: wave j<4 merges partners (2j, 2j+1) -> rows (2j)*16
  if (j < 4) {
    const int l0 = (2 * j) * KNN, r1 = (2 * j + 1) * KNN;
#pragma unroll
    for (int i = 0; i < KNN; i++) {
      fv[i] = poolF[(l0 + i) * QPB + q];
      fid[i] = poolI[(l0 + i) * QPB + q];
    }
    MAX16(fv, fm);
    for (int s = 0; s < KNN; s++) {
      float d = poolF[(r1 + s) * QPB + q];
      if (d < fm) { int m_ = poolI[(r1 + s) * QPB + q]; INSERT16(fv, fid, fm, d, m_); }
    }
#pragma unroll
    for (int i = 0; i < KNN; i++) {
      poolF[(l0 + i) * QPB + q] = fv[i];
      poolI[(l0 + i) * QPB + q] = (unsigned short)fid[i];
    }
  }
  __syncthreads();
  // stage B: wave0: rows0+rows32 ; wave1: rows64+rows96 (ascending order kept)
  if (j < 2) {
    const int l0 = (4 * j) * KNN, r1 = (4 * j + 2) * KNN;
#pragma unroll
    for (int i = 0; i < KNN; i++) {
      fv[i] = poolF[(l0 + i) * QPB + q];
      fid[i] = poolI[(l0 + i) * QPB + q];
    }
    MAX16(fv, fm);
    for (int s = 0; s < KNN; s++) {
      float d = poolF[(r1 + s) * QPB + q];
      if (d < fm) { int m_ = poolI[(r1 + s) * QPB + q]; INSERT16(fv, fid, fm, d, m_); }
    }
#pragma unroll
    for (int i = 0; i < KNN; i++) {
      poolF[(l0 + i) * QPB + q] = fv[i];
      poolI[(l0 + i) * QPB + q] = (unsigned short)fid[i];
    }
  }
  __syncthreads();
  // stage C: wave0 merges rows0 + rows64 -> final ids in poolI rows 0..15
  if (j == 0) {
#pragma unroll
    for (int i = 0; i < KNN; i++) {
      fv[i] = poolF[i * QPB + q];
      fid[i] = poolI[i * QPB + q];
    }
    MAX16(fv, fm);
    for (int s = 0; s < KNN; s++) {
      float d = poolF[(4 * KNN + s) * QPB + q];
      if (d < fm) { int m_ = poolI[(4 * KNN + s) * QPB + q]; INSERT16(fv, fid, fm, d, m_); }
    }
#pragma unroll
    for (int i = 0; i < KNN; i++) poolI[i * QPB + q] = (unsigned short)fid[i];
  }
  __syncthreads();

  // gather neighbors (2 per wave-slot) into poolF rows 0..63
#pragma unroll
  for (int kk = 0; kk < 2; kk++) {
    int k = j * 2 + kk;
    int m = poolI[k * QPB + q];
    float4 c = pk[((size_t)b << 13) + m];
    float dx = __fsub_rn(c.x, qx), dy = __fsub_rn(c.y, qy), dz = __fsub_rn(c.z, qz);
    float dsq = __fadd_rn(__fadd_rn(__fmul_rn(dx, dx), __fmul_rn(dy, dy)),
                          __fmul_rn(dz, dz));
    poolF[k * QPB + q] = c.x;
    poolF[(KNN + k) * QPB + q] = c.y;
    poolF[(2 * KNN + k) * QPB + q] = c.z;
    poolF[(3 * KNN + k) * QPB + q] = dsq;
  }
  __syncthreads();

  float fo[8];
  {
    float nx[KNN], ny[KNN], nz[KNN], nd[KNN];
#pragma unroll
    for (int k = 0; k < KNN; k++) {
      nx[k] = poolF[k * QPB + q];
      ny[k] = poolF[(KNN + k) * QPB + q];
      nz[k] = poolF[(2 * KNN + k) * QPB + q];
      nd[k] = poolF[(3 * KNN + k) * QPB + q];
    }
#pragma unroll
    for (int oi = 0; oi < 8; oi++) {
      int o = j * 8 + oi;
      float4 pA = prmL[o], pB = prmL[HDIM + o];
      float basev = fmaf(qz, pA.z, fmaf(qy, pA.y, fmaf(qx, pA.x, pA.w)));
      float mx = -INF;
#pragma unroll
      for (int k = 0; k < KNN; k++) {
        float tv = fmaf(nz[k], pB.z,
                   fmaf(ny[k], pB.y,
                   fmaf(nx[k], pB.x, __fmul_rn(nd[k], pB.w))));
        mx = fmaxf(mx, tv);
      }
      fo[oi] = basev + mx;
    }
  }
  __syncthreads();  // pool free -> reuse for ws + feature tile

  // stage ws [128][64] into poolF (32 KB), feature tile [64][64] into poolI (16 KB)
  float* wsL = poolF;
  float* feL = (float*)poolI;
  for (int i = t; i < DOUT * DIN; i += NTHR) wsL[i] = wsM[i];
#pragma unroll
  for (int r = 0; r < 8; r++) {
    int c = j * 8 + r;
    feL[c * QPB + q] = feature[(size_t)(b * DIN + c) * N_ + n0 + q];
  }
  __syncthreads();

  // shortcut GEMM: wave j computes outputs o=j*8..j*8+7 and o+64 for its query q
  float acc[16];
#pragma unroll
  for (int oi = 0; oi < 16; oi++) acc[oi] = 0.f;
  for (int c4 = 0; c4 < DIN / 4; c4++) {
    float f0 = feL[(4 * c4 + 0) * QPB + q];
    float f1 = feL[(4 * c4 + 1) * QPB + q];
    float f2 = feL[(4 * c4 + 2) * QPB + q];
    float f3 = feL[(4 * c4 + 3) * QPB + q];
#pragma unroll
    for (int oi = 0; oi < 16; oi++) {
      int o = (oi < 8) ? (j * 8 + oi) : (64 + j * 8 + oi - 8);
      float4 w = ((const float4*)(wsL + o * DIN))[c4];  // wave-uniform broadcast
      acc[oi] = fmaf(w.x, f0, acc[oi]);
      acc[oi] = fmaf(w.y, f1, acc[oi]);
      acc[oi] = fmaf(w.z, f2, acc[oi]);
      acc[oi] = fmaf(w.w, f3, acc[oi]);
    }
  }
  float* ob = out + (size_t)b * DOUT * N_ + n0 + q;
#pragma unroll
  for (int oi = 0; oi < 16; oi++) {
    int o = (oi < 8) ? (j * 8 + oi) : (64 + j * 8 + oi - 8);
    ob[(size_t)o * N_] = acc[oi] + bs[o] + fo[oi & 7];
  }
}

extern "C" void kernel_launch(void* const* d_in, const int* in_sizes, int n_in,
                              void* d_out, int out_size, void* d_ws, size_t ws_size,
                              hipStream_t stream) {
  const float* xyz     = (const float*)d_in[0];
  const float* feature = (const float*)d_in[1];
  const float* w1 = (const float*)d_in[2];
  const float* b1 = (const float*)d_in[3];
  const float* w2 = (const float*)d_in[4];
  const float* b2 = (const float*)d_in[5];
  const float* w3 = (const float*)d_in[6];
  const float* b3 = (const float*)d_in[7];
  const float* wsM = (const float*)d_in[8];
  const float* bs  = (const float*)d_in[9];
  float* out = (float*)d_out;

  // workspace: [0,8KB) prm, [8KB, 8KB+512KB) packed pk
  float4* prm = (float4*)d_ws;
  float4* pkB = (float4*)((char*)d_ws + 8192);

  hipLaunchKernelGGL(k_prep, dim3(128), dim3(256), 0, stream,
                     xyz, w1, b1, w2, b2, w3, b3, pkB, prm);
  hipLaunchKernelGGL(k_knn_fe, dim3(B_ * BLOCKS_PER_B), dim3(NTHR), 0, stream,
                     pkB, prm, feature, wsM, bs, out);
}

// Round 2
// 293.873 us; speedup vs baseline: 1.0159x; 1.0159x over previous
//
#include <hip/hip_runtime.h>

#define B_ 4
#define N_ 8192
#define DIN 64
#define HDIM 64
#define DOUT 128
#define KNN 16
#define QPB 64               // queries per block (= lanes per wave)
#define PART 8               // partner waves per query block
#define NTHR (QPB * PART)    // 512 threads / block
#define CHUNK (N_ / PART)    // 1024 candidates per thread
#define CAP 16               // deferred-insert buffer slots per thread
#define TILE 64              // candidates per LDS-staged tile (1KB = 1 DMA instr)
#define NT (CHUNK / TILE)    // 16 tiles per wave
#define BLOCKS_PER_B (N_ / QPB)  // 128
#define GMARGIN 1e-3f        // conservative slack for the g<G fast filter

// async global->LDS DMA: per-lane global source, wave-linear LDS dest (lane*16)
#define GL2LDS(gp, lp)                                             \
  __builtin_amdgcn_global_load_lds(                                \
      (const __attribute__((address_space(1))) void*)(gp),         \
      (__attribute__((address_space(3))) void*)(lp), 16, 0, 0)

// ---------------- K_prep: pack (x,y,z,sq) + compose affine params ----------------
__global__ __launch_bounds__(256) void k_prep(
    const float* __restrict__ xyz,
    const float* __restrict__ w1, const float* __restrict__ b1,
    const float* __restrict__ w2, const float* __restrict__ b2,
    const float* __restrict__ w3, const float* __restrict__ b3,
    float4* __restrict__ pk, float4* __restrict__ prm) {
  const int blk = blockIdx.x, t = threadIdx.x;
  const int b = blk >> 5;
  const int m = ((blk & 31) << 8) + t;
  const float* xb = xyz + (size_t)b * 3 * N_;
  float x = xb[m], y = xb[N_ + m], z = xb[2 * N_ + m];
  float sq = __fadd_rn(__fadd_rn(__fmul_rn(x, x), __fmul_rn(y, y)), __fmul_rn(z, z));
  pk[((size_t)b << 13) + m] = make_float4(x, y, z, sq);

  if (blk == 0) {
    __shared__ float M2[HDIM][10];
    __shared__ float bb[HDIM];
    const int o = t;
    if (o < HDIM) {
      float r[10];
#pragma unroll
      for (int c = 0; c < 10; c++) r[c] = 0.f;
      float s = b2[o];
      for (int l = 0; l < HDIM; l++) {
        float w = w2[o * HDIM + l];
#pragma unroll
        for (int c = 0; c < 10; c++) r[c] = fmaf(w, w1[l * 10 + c], r[c]);
        s = fmaf(w, b1[l], s);
      }
#pragma unroll
      for (int c = 0; c < 10; c++) M2[o][c] = r[c];
      bb[o] = s;
    }
    __syncthreads();
    if (o < HDIM) {
      float r3[10];
#pragma unroll
      for (int c = 0; c < 10; c++) r3[c] = 0.f;
      float bc = b3[o];
      for (int l = 0; l < HDIM; l++) {
        float w = w3[o * HDIM + l];
#pragma unroll
        for (int c = 0; c < 10; c++) r3[c] = fmaf(w, M2[l][c], r3[c]);
        bc = fmaf(w, bb[l], bc);
      }
      prm[o]      = make_float4(r3[0] - r3[6], r3[1] - r3[7], r3[2] - r3[8], bc);
      prm[64 + o] = make_float4(r3[3] + r3[6], r3[4] + r3[7], r3[5] + r3[8], r3[9]);
    }
  }
}

// replace-max insert into unsorted top-16 kept in registers (fully unrolled)
#define INSERT16(VARR, IARR, VMAX, DVAL, MIDX)                    \
  {                                                               \
    bool done = false;                                            \
    _Pragma("unroll") for (int _i = 0; _i < KNN; _i++) {          \
      bool hit = (!done) && (VARR[_i] == VMAX);                   \
      if (hit) { VARR[_i] = (DVAL); IARR[_i] = (MIDX); }          \
      done = done | hit;                                          \
    }                                                             \
    float _a = fmaxf(fmaxf(fmaxf(VARR[0], VARR[1]), fmaxf(VARR[2], VARR[3])),   \
                     fmaxf(fmaxf(VARR[4], VARR[5]), fmaxf(VARR[6], VARR[7])));  \
    float _b = fmaxf(fmaxf(fmaxf(VARR[8], VARR[9]), fmaxf(VARR[10], VARR[11])), \
                     fmaxf(fmaxf(VARR[12], VARR[13]), fmaxf(VARR[14], VARR[15])));\
    VMAX = fmaxf(_a, _b);                                         \
  }

#define MAX16(VARR, VMAX)                                         \
  {                                                               \
    float _a = fmaxf(fmaxf(fmaxf(VARR[0], VARR[1]), fmaxf(VARR[2], VARR[3])),   \
                     fmaxf(fmaxf(VARR[4], VARR[5]), fmaxf(VARR[6], VARR[7])));  \
    float _b = fmaxf(fmaxf(fmaxf(VARR[8], VARR[9]), fmaxf(VARR[10], VARR[11])), \
                     fmaxf(fmaxf(VARR[12], VARR[13]), fmaxf(VARR[14], VARR[15])));\
    VMAX = fmaxf(_a, _b);                                         \
  }

// drain deferred buffer through INSERT16, publish tau, tighten gate + filter const
#define FLUSH()                                                   \
  {                                                               \
    for (int c_ = 0; c_ < cnt; c_++) {                            \
      float fd_ = poolF[c_ * NTHR + t];                           \
      int fm_ = poolI[c_ * NTHR + t];                             \
      if (fd_ < vmax) { INSERT16(v, id, vmax, fd_, fm_); }        \
    }                                                             \
    cnt = 0;                                                      \
    atomicMin(&tau[q], __float_as_uint(vmax));                    \
    gate = fminf(vmax, __uint_as_float(tau[q]));                  \
    G = __fadd_rn(__fsub_rn(gate, qs), GMARGIN);                  \
  }

// ---------------- K1: fused kNN + fe + shortcut + output ----------------
// block: 64 queries x 8 partner waves; wave j scans candidates [j*1024,(j+1)*1024).
// Candidate stream is staged per-wave into LDS via async global_load_lds DMA
// (1KB tiles, double-buffered, counted vmcnt) and consumed with wave-uniform
// ds_read_b128 broadcasts -- this keeps the stream on the high-MLP vector
// memory path instead of the scalar cache (whose few outstanding-miss slots
// serialized the old s_load stream). No LDS reads in the common path other
// than the tile broadcast; gate/G refresh only at FLUSH. Fast filter g<G
// (3 fma + cmp), conservative by GMARGIN; exact reference-rounded d only on push.
__global__ __launch_bounds__(NTHR, 4) void k_knn_fe(
    const float4* __restrict__ pk, const float4* __restrict__ prm,
    const float* __restrict__ feature, const float* __restrict__ wsM,
    const float* __restrict__ bs, float* __restrict__ out) {
  const int blk = blockIdx.x;
  const int b  = blk / BLOCKS_PER_B;
  const int n0 = (blk % BLOCKS_PER_B) * QPB;
  const int t = threadIdx.x;
  const int q = t & 63;
  const int j = __builtin_amdgcn_readfirstlane(t >> 6);  // wave-uniform partner id

  __shared__ unsigned tau[QPB];
  __shared__ float4 prmL[2 * HDIM];
  // 48 KB pool, time-multiplexed:
  //  scan:   poolF[c*512+t] (32KB), poolI[c*512+t] (16KB)      (c < CAP)
  //  merge:  rows r<128: poolF[r*64+q], poolI[r*64+q]
  //  gather: rows r<64 of poolF = neighbor x/y/z/dsq
  //  epilogue: poolF = ws[128][64], poolI-as-float = feature tile [64][64]
  __shared__ alignas(16) float poolF[CAP * NTHR];
  __shared__ alignas(16) unsigned short poolI[CAP * NTHR];
  // per-wave double-buffered candidate tiles (16 KB total)
  __shared__ alignas(16) float4 tiles[PART][2][TILE];

  if (t < QPB) tau[t] = 0x7f800000u;  // +inf
  for (int i = t; i < 2 * HDIM; i += NTHR) prmL[i] = prm[i];

  const float4 qv = pk[((size_t)b << 13) + n0 + q];
  const float qx = qv.x, qy = qv.y, qz = qv.z, qs = qv.w;
  const float nx2 = -2.0f * qx, ny2 = -2.0f * qy, nz2 = -2.0f * qz;

  const float INF = __uint_as_float(0x7f800000u);
  float v[KNN]; int id[KNN];
  float vmax, gate, G;
  int cnt = 0;
  __syncthreads();

  const float4* pj = pk + ((size_t)b << 13) + j * CHUNK;

  // kick off tile 0 DMA; warm-start work below hides its latency
  GL2LDS(pj + q, &tiles[j][0][0]);

  // warm start: first 16 candidates fill the list directly (no gating, no flush
  // storm; list order = scan order so tie semantics match the gated path)
  {
    float4 c[KNN];
#pragma unroll
    for (int e = 0; e < KNN; e++) c[e] = pj[e];
#pragma unroll
    for (int e = 0; e < KNN; e++) {
      float dot = fmaf(c[e].z, qz, fmaf(c[e].y, qy, __fmul_rn(c[e].x, qx)));
      v[e] = __fsub_rn(__fadd_rn(qs, c[e].w), __fmul_rn(2.0f, dot));
      id[e] = j * CHUNK + e;
    }
    MAX16(v, vmax);
    atomicMin(&tau[q], __float_as_uint(vmax));   // publish early so partners gate
    gate = fminf(vmax, __uint_as_float(tau[q]));
    G = __fadd_rn(__fsub_rn(gate, qs), GMARGIN);
  }

  for (int T = 0; T < NT; T++) {
    if (T + 1 < NT) {
      GL2LDS(pj + (T + 1) * TILE + q, &tiles[j][(T + 1) & 1][0]);
      asm volatile("s_waitcnt vmcnt(1)" ::: "memory");  // tile T landed
    } else {
      asm volatile("s_waitcnt vmcnt(0)" ::: "memory");
    }
    const float4* tb = &tiles[j][T & 1][0];
    const int m0 = j * CHUNK + T * TILE;
    const int g0 = (T == 0) ? 2 : 0;  // tile 0: skip warm-start candidates 0..15
    for (int gr = g0; gr < TILE / 8; gr++) {
      if (__any(cnt > CAP - 8)) { FLUSH(); }
      float4 c[8];
#pragma unroll
      for (int e = 0; e < 8; e++) c[e] = tb[gr * 8 + e];  // uniform ds_read_b128 x8
#pragma unroll
      for (int e = 0; e < 8; e++) {
        // fast filter: g = cw - 2*dot (fused); strict superset of d<gate by GMARGIN
        float gg = fmaf(c[e].x, nx2, fmaf(c[e].y, ny2, fmaf(c[e].z, nz2, c[e].w)));
        if (gg < G) {
          // exact reference rounding only on the rare push; FLUSH re-filters exactly
          float dot = fmaf(c[e].z, qz, fmaf(c[e].y, qy, __fmul_rn(c[e].x, qx)));
          float d = __fsub_rn(__fadd_rn(qs, c[e].w), __fmul_rn(2.0f, dot));
          poolF[cnt * NTHR + t] = d;
          poolI[cnt * NTHR + t] = (unsigned short)(m0 + gr * 8 + e);
          cnt++;
        }
      }
    }
  }
  FLUSH();
  __syncthreads();

  // publish per-thread lists: rows j*16+i (ascending-m order across j)
#pragma unroll
  for (int i = 0; i < KNN; i++) {
    poolF[(j * KNN + i) * QPB + q] = v[i];
    poolI[(j * KNN + i) * QPB + q] = (unsigned short)id[i];
  }
  __syncthreads();

  float fv[KNN]; int fid[KNN]; float fm = INF;
  // stage A: wave j<4 merges partners (2j, 2j+1) -> rows (2j)*16
  if (j < 4) {
    const int l0 = (2 * j) * KNN, r1 = (2 * j + 1) * KNN;
#pragma unroll
    for (int i = 0; i < KNN; i++) {
      fv[i] = poolF[(l0 + i) * QPB + q];
      fid[i] = poolI[(l0 + i) * QPB + q];
    }
    MAX16(fv, fm);
    for (int s = 0; s < KNN; s++) {
      float d = poolF[(r1 + s) * QPB + q];
      if (d < fm) { int m_ = poolI[(r1 + s) * QPB + q]; INSERT16(fv, fid, fm, d, m_); }
    }
#pragma unroll
    for (int i = 0; i < KNN; i++) {
      poolF[(l0 + i) * QPB + q] = fv[i];
      poolI[(l0 + i) * QPB + q] = (unsigned short)fid[i];
    }
  }
  __syncthreads();
  // stage B: wave0: rows0+rows32 ; wave1: rows64+rows96 (ascending order kept)
  if (j < 2) {
    const int l0 = (4 * j) * KNN, r1 = (4 * j + 2) * KNN;
#pragma unroll
    for (int i = 0; i < KNN; i++) {
      fv[i] = poolF[(l0 + i) * QPB + q];
      fid[i] = poolI[(l0 + i) * QPB + q];
    }
    MAX16(fv, fm);
    for (int s = 0; s < KNN; s++) {
      float d = poolF[(r1 + s) * QPB + q];
      if (d < fm) { int m_ = poolI[(r1 + s) * QPB + q]; INSERT16(fv, fid, fm, d, m_); }
    }
#pragma unroll
    for (int i = 0; i < KNN; i++) {
      poolF[(l0 + i) * QPB + q] = fv[i];
      poolI[(l0 + i) * QPB + q] = (unsigned short)fid[i];
    }
  }
  __syncthreads();
  // stage C: wave0 merges rows0 + rows64 -> final ids in poolI rows 0..15
  if (j == 0) {
#pragma unroll
    for (int i = 0; i < KNN; i++) {
      fv[i] = poolF[i * QPB + q];
      fid[i] = poolI[i * QPB + q];
    }
    MAX16(fv, fm);
    for (int s = 0; s < KNN; s++) {
      float d = poolF[(4 * KNN + s) * QPB + q];
      if (d < fm) { int m_ = poolI[(4 * KNN + s) * QPB + q]; INSERT16(fv, fid, fm, d, m_); }
    }
#pragma unroll
    for (int i = 0; i < KNN; i++) poolI[i * QPB + q] = (unsigned short)fid[i];
  }
  __syncthreads();

  // gather neighbors (2 per wave-slot) into poolF rows 0..63
#pragma unroll
  for (int kk = 0; kk < 2; kk++) {
    int k = j * 2 + kk;
    int m = poolI[k * QPB + q];
    float4 c = pk[((size_t)b << 13) + m];
    float dx = __fsub_rn(c.x, qx), dy = __fsub_rn(c.y, qy), dz = __fsub_rn(c.z, qz);
    float dsq = __fadd_rn(__fadd_rn(__fmul_rn(dx, dx), __fmul_rn(dy, dy)),
                          __fmul_rn(dz, dz));
    poolF[k * QPB + q] = c.x;
    poolF[(KNN + k) * QPB + q] = c.y;
    poolF[(2 * KNN + k) * QPB + q] = c.z;
    poolF[(3 * KNN + k) * QPB + q] = dsq;
  }
  __syncthreads();

  float fo[8];
  {
    float nx[KNN], ny[KNN], nz[KNN], nd[KNN];
#pragma unroll
    for (int k = 0; k < KNN; k++) {
      nx[k] = poolF[k * QPB + q];
      ny[k] = poolF[(KNN + k) * QPB + q];
      nz[k] = poolF[(2 * KNN + k) * QPB + q];
      nd[k] = poolF[(3 * KNN + k) * QPB + q];
    }
#pragma unroll
    for (int oi = 0; oi < 8; oi++) {
      int o = j * 8 + oi;
      float4 pA = prmL[o], pB = prmL[HDIM + o];
      float basev = fmaf(qz, pA.z, fmaf(qy, pA.y, fmaf(qx, pA.x, pA.w)));
      float mx = -INF;
#pragma unroll
      for (int k = 0; k < KNN; k++) {
        float tv = fmaf(nz[k], pB.z,
                   fmaf(ny[k], pB.y,
                   fmaf(nx[k], pB.x, __fmul_rn(nd[k], pB.w))));
        mx = fmaxf(mx, tv);
      }
      fo[oi] = basev + mx;
    }
  }
  __syncthreads();  // pool free -> reuse for ws + feature tile

  // stage ws [128][64] into poolF (32 KB), feature tile [64][64] into poolI (16 KB)
  float* wsL = poolF;
  float* feL = (float*)poolI;
  for (int i = t; i < DOUT * DIN; i += NTHR) wsL[i] = wsM[i];
#pragma unroll
  for (int r = 0; r < 8; r++) {
    int c = j * 8 + r;
    feL[c * QPB + q] = feature[(size_t)(b * DIN + c) * N_ + n0 + q];
  }
  __syncthreads();

  // shortcut GEMM: wave j computes outputs o=j*8..j*8+7 and o+64 for its query q
  float acc[16];
#pragma unroll
  for (int oi = 0; oi < 16; oi++) acc[oi] = 0.f;
  for (int c4 = 0; c4 < DIN / 4; c4++) {
    float f0 = feL[(4 * c4 + 0) * QPB + q];
    float f1 = feL[(4 * c4 + 1) * QPB + q];
    float f2 = feL[(4 * c4 + 2) * QPB + q];
    float f3 = feL[(4 * c4 + 3) * QPB + q];
#pragma unroll
    for (int oi = 0; oi < 16; oi++) {
      int o = (oi < 8) ? (j * 8 + oi) : (64 + j * 8 + oi - 8);
      float4 w = ((const float4*)(wsL + o * DIN))[c4];  // wave-uniform broadcast
      acc[oi] = fmaf(w.x, f0, acc[oi]);
      acc[oi] = fmaf(w.y, f1, acc[oi]);
      acc[oi] = fmaf(w.z, f2, acc[oi]);
      acc[oi] = fmaf(w.w, f3, acc[oi]);
    }
  }
  float* ob = out + (size_t)b * DOUT * N_ + n0 + q;
#pragma unroll
  for (int oi = 0; oi < 16; oi++) {
    int o = (oi < 8) ? (j * 8 + oi) : (64 + j * 8 + oi - 8);
    ob[(size_t)o * N_] = acc[oi] + bs[o] + fo[oi & 7];
  }
}

extern "C" void kernel_launch(void* const* d_in, const int* in_sizes, int n_in,
                              void* d_out, int out_size, void* d_ws, size_t ws_size,
                              hipStream_t stream) {
  const float* xyz     = (const float*)d_in[0];
  const float* feature = (const float*)d_in[1];
  const float* w1 = (const float*)d_in[2];
  const float* b1 = (const float*)d_in[3];
  const float* w2 = (const float*)d_in[4];
  const float* b2 = (const float*)d_in[5];
  const float* w3 = (const float*)d_in[6];
  const float* b3 = (const float*)d_in[7];
  const float* wsM = (const float*)d_in[8];
  const float* bs  = (const float*)d_in[9];
  float* out = (float*)d_out;

  // workspace: [0,8KB) prm, [8KB, 8KB+512KB) packed pk
  float4* prm = (float4*)d_ws;
  float4* pkB = (float4*)((char*)d_ws + 8192);

  hipLaunchKernelGGL(k_prep, dim3(128), dim3(256), 0, stream,
                     xyz, w1, b1, w2, b2, w3, b3, pkB, prm);
  hipLaunchKernelGGL(k_knn_fe, dim3(B_ * BLOCKS_PER_B), dim3(NTHR), 0, stream,
                     pkB, prm, feature, wsM, bs, out);
}

// Round 3
// 274.348 us; speedup vs baseline: 1.0882x; 1.0712x over previous
//
#include <hip/hip_runtime.h>

#define B_ 4
#define N_ 8192
#define DIN 64
#define HDIM 64
#define DOUT 128
#define KNN 16
#define QPB 64               // queries per block (= lanes per wave)
#define PART 8               // partner waves per query block
#define NTHR (QPB * PART)    // 512 threads / block
#define CHUNK (N_ / PART)    // 1024 candidates per thread
#define CAP 16               // deferred-insert buffer slots per thread
#define CAPP 17              // padded per-lane stride (odd -> conflict-free LDS)
#define BLOCKS_PER_B (N_ / QPB)  // 128

// ---------------- K_prep: pack (x,y,z,sq) + compose affine params ----------------
__global__ __launch_bounds__(256) void k_prep(
    const float* __restrict__ xyz,
    const float* __restrict__ w1, const float* __restrict__ b1,
    const float* __restrict__ w2, const float* __restrict__ b2,
    const float* __restrict__ w3, const float* __restrict__ b3,
    float4* __restrict__ pk, float4* __restrict__ prm) {
  const int blk = blockIdx.x, t = threadIdx.x;
  const int b = blk >> 5;
  const int m = ((blk & 31) << 8) + t;
  const float* xb = xyz + (size_t)b * 3 * N_;
  float x = xb[m], y = xb[N_ + m], z = xb[2 * N_ + m];
  float sq = __fadd_rn(__fadd_rn(__fmul_rn(x, x), __fmul_rn(y, y)), __fmul_rn(z, z));
  pk[((size_t)b << 13) + m] = make_float4(x, y, z, sq);

  if (blk == 0) {
    __shared__ float M2[HDIM][10];
    __shared__ float bb[HDIM];
    const int o = t;
    if (o < HDIM) {
      float r[10];
#pragma unroll
      for (int c = 0; c < 10; c++) r[c] = 0.f;
      float s = b2[o];
      for (int l = 0; l < HDIM; l++) {
        float w = w2[o * HDIM + l];
#pragma unroll
        for (int c = 0; c < 10; c++) r[c] = fmaf(w, w1[l * 10 + c], r[c]);
        s = fmaf(w, b1[l], s);
      }
#pragma unroll
      for (int c = 0; c < 10; c++) M2[o][c] = r[c];
      bb[o] = s;
    }
    __syncthreads();
    if (o < HDIM) {
      float r3[10];
#pragma unroll
      for (int c = 0; c < 10; c++) r3[c] = 0.f;
      float bc = b3[o];
      for (int l = 0; l < HDIM; l++) {
        float w = w3[o * HDIM + l];
#pragma unroll
        for (int c = 0; c < 10; c++) r3[c] = fmaf(w, M2[l][c], r3[c]);
        bc = fmaf(w, bb[l], bc);
      }
      prm[o]      = make_float4(r3[0] - r3[6], r3[1] - r3[7], r3[2] - r3[8], bc);
      prm[64 + o] = make_float4(r3[3] + r3[6], r3[4] + r3[7], r3[5] + r3[8], r3[9]);
    }
  }
}

// max of 16 via v_max3-friendly triple nesting (8 instrs instead of 15)
#define MAX16(VARR, VMAX)                                                     \
  {                                                                           \
    float _m0 = fmaxf(fmaxf(VARR[0], VARR[1]), VARR[2]);                      \
    float _m1 = fmaxf(fmaxf(VARR[3], VARR[4]), VARR[5]);                      \
    float _m2 = fmaxf(fmaxf(VARR[6], VARR[7]), VARR[8]);                      \
    float _m3 = fmaxf(fmaxf(VARR[9], VARR[10]), VARR[11]);                    \
    float _m4 = fmaxf(fmaxf(VARR[12], VARR[13]), VARR[14]);                   \
    float _a = fmaxf(fmaxf(_m0, _m1), _m2);                                   \
    float _b = fmaxf(fmaxf(_m3, _m4), VARR[15]);                              \
    VMAX = fmaxf(_a, _b);                                                     \
  }

// replace-max insert into unsorted top-16 kept in registers (fully unrolled)
#define INSERT16(VARR, IARR, VMAX, DVAL, MIDX)                    \
  {                                                               \
    bool done = false;                                            \
    _Pragma("unroll") for (int _i = 0; _i < KNN; _i++) {          \
      bool hit = (!done) && (VARR[_i] == VMAX);                   \
      if (hit) { VARR[_i] = (DVAL); IARR[_i] = (MIDX); }          \
      done = done | hit;                                          \
    }                                                             \
    MAX16(VARR, VMAX);                                            \
  }

// drain deferred buffer through INSERT16, publish tau, tighten gate
#define FLUSH()                                                   \
  {                                                               \
    for (int c_ = 0; c_ < cnt; c_++) {                            \
      float fd_ = poolF[lbase + c_];                              \
      int fm_ = poolI[lbase + c_];                                \
      if (fd_ < vmax) { INSERT16(v, id, vmax, fd_, fm_); }        \
    }                                                             \
    cnt = 0;                                                      \
    atomicMin(&tau[q], __float_as_uint(vmax));                    \
    gate = fminf(vmax, __uint_as_float(tau[q]));                  \
  }

// ---------------- K1: fused kNN + fe + shortcut + output ----------------
// block: 64 queries x 8 partner waves; wave j scans candidates [j*1024,(j+1)*1024)
// via wave-uniform scalar loads (L2-resident, proven equal to DMA/vector paths).
// Hot path per candidate is EXACT reference-rounded d in 5 VALU + cmp:
//   d = fmaf(-2, dot, qs+cw)  ==  (qs+cw) - 2*dot bit-exactly (2*dot is exact).
// Push body is 1-VALU addressing (pool[t*17+cnt], odd stride = conflict-free)
// + 2 ds_writes; no recompute, no margin. FLUSH re-filters by evolving vmax.
__global__ __launch_bounds__(NTHR, 4) void k_knn_fe(
    const float4* __restrict__ pk, const float4* __restrict__ prm,
    const float* __restrict__ feature, const float* __restrict__ wsM,
    const float* __restrict__ bs, float* __restrict__ out) {
  const int blk = blockIdx.x;
  const int b  = blk / BLOCKS_PER_B;
  const int n0 = (blk % BLOCKS_PER_B) * QPB;
  const int t = threadIdx.x;
  const int q = t & 63;
  const int j = __builtin_amdgcn_readfirstlane(t >> 6);  // wave-uniform partner id
  const int lbase = t * CAPP;                            // per-lane buffer base

  __shared__ unsigned tau[QPB];
  __shared__ float4 prmL[2 * HDIM];
  // ~52 KB pool, time-multiplexed:
  //  scan:   poolF[t*17+c] (34.8KB), poolI[t*17+c] (17.4KB)     (c < CAP)
  //  merge:  rows r<128: poolF[r*64+q], poolI[r*64+q]
  //  gather: rows r<64 of poolF = neighbor x/y/z/dsq
  //  epilogue: poolF = ws[128][64], poolI-as-float = feature tile [64][64]
  __shared__ alignas(16) float poolF[CAPP * NTHR];
  __shared__ alignas(16) unsigned short poolI[CAPP * NTHR];

  if (t < QPB) tau[t] = 0x7f800000u;  // +inf
  for (int i = t; i < 2 * HDIM; i += NTHR) prmL[i] = prm[i];

  const float4 qv = pk[((size_t)b << 13) + n0 + q];
  const float qx = qv.x, qy = qv.y, qz = qv.z, qs = qv.w;

  const float INF = __uint_as_float(0x7f800000u);
  float v[KNN]; int id[KNN];
  float vmax, gate;
  int cnt = 0;
  __syncthreads();

  const float4* pj = pk + ((size_t)b << 13) + j * CHUNK;

  // warm start: first 16 candidates fill the list directly (no gating, no flush
  // storm; list order = scan order so tie semantics match the gated path)
  {
    float4 c[KNN];
#pragma unroll
    for (int e = 0; e < KNN; e++) c[e] = pj[e];
#pragma unroll
    for (int e = 0; e < KNN; e++) {
      float dot = fmaf(c[e].z, qz, fmaf(c[e].y, qy, __fmul_rn(c[e].x, qx)));
      v[e] = fmaf(-2.0f, dot, __fadd_rn(qs, c[e].w));  // == (qs+cw) - 2*dot exactly
      id[e] = j * CHUNK + e;
    }
    MAX16(v, vmax);
    atomicMin(&tau[q], __float_as_uint(vmax));   // publish early so partners gate
    gate = fminf(vmax, __uint_as_float(tau[q]));
  }

  unsigned tnext = tau[q];  // software-pipelined gate refresh
  for (int u0 = KNN; u0 < CHUNK; u0 += 8) {
    if (__any(cnt > CAP - 8)) { FLUSH(); }
    gate = fminf(gate, __uint_as_float(tnext));  // partners' progress (1 iter stale)
    tnext = tau[q];                              // issue now, consume next iter
    float4 c[8];
#pragma unroll
    for (int e = 0; e < 8; e++) c[e] = pj[u0 + e];  // 8 uniform s_load_dwordx4
#pragma unroll
    for (int e = 0; e < 8; e++) {
      float dot = fmaf(c[e].z, qz, fmaf(c[e].y, qy, __fmul_rn(c[e].x, qx)));
      float d = fmaf(-2.0f, dot, __fadd_rn(qs, c[e].w));  // exact reference rounding
      if (d < gate) {  // thin push: 1 VALU addr + 2 ds_write + cnt++
        poolF[lbase + cnt] = d;
        poolI[lbase + cnt] = (unsigned short)(j * CHUNK + u0 + e);
        cnt++;
      }
    }
  }
  FLUSH();
  __syncthreads();

  // publish per-thread lists: rows j*16+i (ascending-m order across j)
#pragma unroll
  for (int i = 0; i < KNN; i++) {
    poolF[(j * KNN + i) * QPB + q] = v[i];
    poolI[(j * KNN + i) * QPB + q] = (unsigned short)id[i];
  }
  __syncthreads();

  float fv[KNN]; int fid[KNN]; float fm = INF;
  // stage A: wave j<4 merges partners (2j, 2j+1) -> rows (2j)*16
  if (j < 4) {
    const int l0 = (2 * j) * KNN, r1 = (2 * j + 1) * KNN;
#pragma unroll
    for (int i = 0; i < KNN; i++) {
      fv[i] = poolF[(l0 + i) * QPB + q];
      fid[i] = poolI[(l0 + i) * QPB + q];
    }
    MAX16(fv, fm);
    for (int s = 0; s < KNN; s++) {
      float d = poolF[(r1 + s) * QPB + q];
      if (d < fm) { int m_ = poolI[(r1 + s) * QPB + q]; INSERT16(fv, fid, fm, d, m_); }
    }
#pragma unroll
    for (int i = 0; i < KNN; i++) {
      poolF[(l0 + i) * QPB + q] = fv[i];
      poolI[(l0 + i) * QPB + q] = (unsigned short)fid[i];
    }
  }
  __syncthreads();
  // stage B: wave0: rows0+rows32 ; wave1: rows64+rows96 (ascending order kept)
  if (j < 2) {
    const int l0 = (4 * j) * KNN, r1 = (4 * j + 2) * KNN;
#pragma unroll
    for (int i = 0; i < KNN; i++) {
      fv[i] = poolF[(l0 + i) * QPB + q];
      fid[i] = poolI[(l0 + i) * QPB + q];
    }
    MAX16(fv, fm);
    for (int s = 0; s < KNN; s++) {
      float d = poolF[(r1 + s) * QPB + q];
      if (d < fm) { int m_ = poolI[(r1 + s) * QPB + q]; INSERT16(fv, fid, fm, d, m_); }
    }
#pragma unroll
    for (int i = 0; i < KNN; i++) {
      poolF[(l0 + i) * QPB + q] = fv[i];
      poolI[(l0 + i) * QPB + q] = (unsigned short)fid[i];
    }
  }
  __syncthreads();
  // stage C: wave0 merges rows0 + rows64 -> final ids in poolI rows 0..15
  if (j == 0) {
#pragma unroll
    for (int i = 0; i < KNN; i++) {
      fv[i] = poolF[i * QPB + q];
      fid[i] = poolI[i * QPB + q];
    }
    MAX16(fv, fm);
    for (int s = 0; s < KNN; s++) {
      float d = poolF[(4 * KNN + s) * QPB + q];
      if (d < fm) { int m_ = poolI[(4 * KNN + s) * QPB + q]; INSERT16(fv, fid, fm, d, m_); }
    }
#pragma unroll
    for (int i = 0; i < KNN; i++) poolI[i * QPB + q] = (unsigned short)fid[i];
  }
  __syncthreads();

  // gather neighbors (2 per wave-slot) into poolF rows 0..63
#pragma unroll
  for (int kk = 0; kk < 2; kk++) {
    int k = j * 2 + kk;
    int m = poolI[k * QPB + q];
    float4 c = pk[((size_t)b << 13) + m];
    float dx = __fsub_rn(c.x, qx), dy = __fsub_rn(c.y, qy), dz = __fsub_rn(c.z, qz);
    float dsq = __fadd_rn(__fadd_rn(__fmul_rn(dx, dx), __fmul_rn(dy, dy)),
                          __fmul_rn(dz, dz));
    poolF[k * QPB + q] = c.x;
    poolF[(KNN + k) * QPB + q] = c.y;
    poolF[(2 * KNN + k) * QPB + q] = c.z;
    poolF[(3 * KNN + k) * QPB + q] = dsq;
  }
  __syncthreads();

  float fo[8];
  {
    float nx[KNN], ny[KNN], nz[KNN], nd[KNN];
#pragma unroll
    for (int k = 0; k < KNN; k++) {
      nx[k] = poolF[k * QPB + q];
      ny[k] = poolF[(KNN + k) * QPB + q];
      nz[k] = poolF[(2 * KNN + k) * QPB + q];
      nd[k] = poolF[(3 * KNN + k) * QPB + q];
    }
#pragma unroll
    for (int oi = 0; oi < 8; oi++) {
      int o = j * 8 + oi;
      float4 pA = prmL[o], pB = prmL[HDIM + o];
      float basev = fmaf(qz, pA.z, fmaf(qy, pA.y, fmaf(qx, pA.x, pA.w)));
      float mx = -INF;
#pragma unroll
      for (int k = 0; k < KNN; k++) {
        float tv = fmaf(nz[k], pB.z,
                   fmaf(ny[k], pB.y,
                   fmaf(nx[k], pB.x, __fmul_rn(nd[k], pB.w))));
        mx = fmaxf(mx, tv);
      }
      fo[oi] = basev + mx;
    }
  }
  __syncthreads();  // pool free -> reuse for ws + feature tile

  // stage ws [128][64] into poolF (32 KB), feature tile [64][64] into poolI (16 KB)
  float* wsL = poolF;
  float* feL = (float*)poolI;
  for (int i = t; i < DOUT * DIN; i += NTHR) wsL[i] = wsM[i];
#pragma unroll
  for (int r = 0; r < 8; r++) {
    int c = j * 8 + r;
    feL[c * QPB + q] = feature[(size_t)(b * DIN + c) * N_ + n0 + q];
  }
  __syncthreads();

  // shortcut GEMM: wave j computes outputs o=j*8..j*8+7 and o+64 for its query q
  float acc[16];
#pragma unroll
  for (int oi = 0; oi < 16; oi++) acc[oi] = 0.f;
  for (int c4 = 0; c4 < DIN / 4; c4++) {
    float f0 = feL[(4 * c4 + 0) * QPB + q];
    float f1 = feL[(4 * c4 + 1) * QPB + q];
    float f2 = feL[(4 * c4 + 2) * QPB + q];
    float f3 = feL[(4 * c4 + 3) * QPB + q];
#pragma unroll
    for (int oi = 0; oi < 16; oi++) {
      int o = (oi < 8) ? (j * 8 + oi) : (64 + j * 8 + oi - 8);
      float4 w = ((const float4*)(wsL + o * DIN))[c4];  // wave-uniform broadcast
      acc[oi] = fmaf(w.x, f0, acc[oi]);
      acc[oi] = fmaf(w.y, f1, acc[oi]);
      acc[oi] = fmaf(w.z, f2, acc[oi]);
      acc[oi] = fmaf(w.w, f3, acc[oi]);
    }
  }
  float* ob = out + (size_t)b * DOUT * N_ + n0 + q;
#pragma unroll
  for (int oi = 0; oi < 16; oi++) {
    int o = (oi < 8) ? (j * 8 + oi) : (64 + j * 8 + oi - 8);
    ob[(size_t)o * N_] = acc[oi] + bs[o] + fo[oi & 7];
  }
}

extern "C" void kernel_launch(void* const* d_in, const int* in_sizes, int n_in,
                              void* d_out, int out_size, void* d_ws, size_t ws_size,
                              hipStream_t stream) {
  const float* xyz     = (const float*)d_in[0];
  const float* feature = (const float*)d_in[1];
  const float* w1 = (const float*)d_in[2];
  const float* b1 = (const float*)d_in[3];
  const float* w2 = (const float*)d_in[4];
  const float* b2 = (const float*)d_in[5];
  const float* w3 = (const float*)d_in[6];
  const float* b3 = (const float*)d_in[7];
  const float* wsM = (const float*)d_in[8];
  const float* bs  = (const float*)d_in[9];
  float* out = (float*)d_out;

  // workspace: [0,8KB) prm, [8KB, 8KB+512KB) packed pk
  float4* prm = (float4*)d_ws;
  float4* pkB = (float4*)((char*)d_ws + 8192);

  hipLaunchKernelGGL(k_prep, dim3(128), dim3(256), 0, stream,
                     xyz, w1, b1, w2, b2, w3, b3, pkB, prm);
  hipLaunchKernelGGL(k_knn_fe, dim3(B_ * BLOCKS_PER_B), dim3(NTHR), 0, stream,
                     pkB, prm, feature, wsM, bs, out);
}

// Round 4
// 263.285 us; speedup vs baseline: 1.1339x; 1.0420x over previous
//
#include <hip/hip_runtime.h>

#define B_ 4
#define N_ 8192
#define DIN 64
#define HDIM 64
#define DOUT 128
#define KNN 16
#define QPB 64               // queries per block (= lanes per wave)
#define PART 8               // partner waves per query block
#define NTHR (QPB * PART)    // 512 threads / block
#define CHUNK (N_ / PART)    // 1024 candidates per thread
#define CAP 16               // deferred-insert buffer slots per thread (idx only)
#define CAPP 17              // padded per-lane stride (ushorts; de-banks pushes)
#define BLOCKS_PER_B (N_ / QPB)  // 128
#define GMARGIN 1e-3f        // conservative slack for the g<G fast filter

// ---------------- K_prep: pack (x,y,z,sq) + compose affine params ----------------
__global__ __launch_bounds__(256) void k_prep(
    const float* __restrict__ xyz,
    const float* __restrict__ w1, const float* __restrict__ b1,
    const float* __restrict__ w2, const float* __restrict__ b2,
    const float* __restrict__ w3, const float* __restrict__ b3,
    float4* __restrict__ pk, float4* __restrict__ prm) {
  const int blk = blockIdx.x, t = threadIdx.x;
  const int b = blk >> 5;
  const int m = ((blk & 31) << 8) + t;
  const float* xb = xyz + (size_t)b * 3 * N_;
  float x = xb[m], y = xb[N_ + m], z = xb[2 * N_ + m];
  float sq = __fadd_rn(__fadd_rn(__fmul_rn(x, x), __fmul_rn(y, y)), __fmul_rn(z, z));
  pk[((size_t)b << 13) + m] = make_float4(x, y, z, sq);

  if (blk == 0) {
    __shared__ float M2[HDIM][10];
    __shared__ float bb[HDIM];
    const int o = t;
    if (o < HDIM) {
      float r[10];
#pragma unroll
      for (int c = 0; c < 10; c++) r[c] = 0.f;
      float s = b2[o];
      for (int l = 0; l < HDIM; l++) {
        float w = w2[o * HDIM + l];
#pragma unroll
        for (int c = 0; c < 10; c++) r[c] = fmaf(w, w1[l * 10 + c], r[c]);
        s = fmaf(w, b1[l], s);
      }
#pragma unroll
      for (int c = 0; c < 10; c++) M2[o][c] = r[c];
      bb[o] = s;
    }
    __syncthreads();
    if (o < HDIM) {
      float r3[10];
#pragma unroll
      for (int c = 0; c < 10; c++) r3[c] = 0.f;
      float bc = b3[o];
      for (int l = 0; l < HDIM; l++) {
        float w = w3[o * HDIM + l];
#pragma unroll
        for (int c = 0; c < 10; c++) r3[c] = fmaf(w, M2[l][c], r3[c]);
        bc = fmaf(w, bb[l], bc);
      }
      prm[o]      = make_float4(r3[0] - r3[6], r3[1] - r3[7], r3[2] - r3[8], bc);
      prm[64 + o] = make_float4(r3[3] + r3[6], r3[4] + r3[7], r3[5] + r3[8], r3[9]);
    }
  }
}

// max of 16 via v_max3-friendly triple nesting
#define MAX16(VARR, VMAX)                                                     \
  {                                                                           \
    float _m0 = fmaxf(fmaxf(VARR[0], VARR[1]), VARR[2]);                      \
    float _m1 = fmaxf(fmaxf(VARR[3], VARR[4]), VARR[5]);                      \
    float _m2 = fmaxf(fmaxf(VARR[6], VARR[7]), VARR[8]);                      \
    float _m3 = fmaxf(fmaxf(VARR[9], VARR[10]), VARR[11]);                    \
    float _m4 = fmaxf(fmaxf(VARR[12], VARR[13]), VARR[14]);                   \
    float _a = fmaxf(fmaxf(_m0, _m1), _m2);                                   \
    float _b = fmaxf(fmaxf(_m3, _m4), VARR[15]);                              \
    VMAX = fmaxf(_a, _b);                                                     \
  }

// replace-max insert into unsorted top-16 kept in registers (fully unrolled)
#define INSERT16(VARR, IARR, VMAX, DVAL, MIDX)                    \
  {                                                               \
    bool done = false;                                            \
    _Pragma("unroll") for (int _i = 0; _i < KNN; _i++) {          \
      bool hit = (!done) && (VARR[_i] == VMAX);                   \
      if (hit) { VARR[_i] = (DVAL); IARR[_i] = (MIDX); }          \
      done = done | hit;                                          \
    }                                                             \
    MAX16(VARR, VMAX);                                            \
  }

// drain idx-only buffer: re-gather candidates from pk (L2, 8-wide batches for
// MLP), recompute EXACT reference-rounded d, insert in push order. Then publish
// tau via atomicMin's returned old value (no LDS read-back) and refresh gate/G.
#define FLUSH()                                                               \
  {                                                                           \
    _Pragma("unroll") for (int c0_ = 0; c0_ < CAP; c0_ += 8) {                \
      int mi_[8]; float4 fc_[8];                                              \
      _Pragma("unroll") for (int e_ = 0; e_ < 8; e_++)                        \
        mi_[e_] = poolI[lbase + c0_ + e_] & (N_ - 1);                         \
      _Pragma("unroll") for (int e_ = 0; e_ < 8; e_++)                        \
        fc_[e_] = pk[bb + mi_[e_]];                                           \
      _Pragma("unroll") for (int e_ = 0; e_ < 8; e_++) {                      \
        if (c0_ + e_ < cnt) {                                                 \
          float dot_ = fmaf(fc_[e_].z, qz,                                    \
                       fmaf(fc_[e_].y, qy, __fmul_rn(fc_[e_].x, qx)));        \
          float d_ = fmaf(-2.0f, dot_, __fadd_rn(qs, fc_[e_].w));             \
          if (d_ < vmax) { INSERT16(v, id, vmax, d_, mi_[e_]); }              \
        }                                                                     \
      }                                                                       \
    }                                                                         \
    cnt = 0;                                                                  \
    unsigned old_ = atomicMin(&tau[q], __float_as_uint(vmax));                \
    gate = fminf(vmax, __uint_as_float(old_));                                \
    G = __fadd_rn(__fsub_rn(gate, qs), GMARGIN);                              \
  }

// process one 8-candidate batch held in wave-uniform registers: 4-VALU filter,
// idx-only push (1 ds_write_b16 + cnt++). No other memory ops.
#define PROC8(CARR, U0)                                                       \
  {                                                                           \
    if (__any(cnt > CAP - 8)) { FLUSH(); }                                    \
    _Pragma("unroll") for (int e = 0; e < 8; e++) {                           \
      float gg = fmaf(CARR[e].x, nx2, fmaf(CARR[e].y, ny2,                    \
                  fmaf(CARR[e].z, nz2, CARR[e].w)));                          \
      if (gg < G) {                                                           \
        poolI[lbase + cnt] = (unsigned short)(jC + (U0) + e);                 \
        cnt++;                                                                \
      }                                                                       \
    }                                                                         \
  }

// ---------------- K1: fused kNN + fe + shortcut + output ----------------
// block: 64 queries x 8 partner waves; wave j scans candidates [j*1024,(j+1)*1024)
// via wave-uniform scalar loads, ping-pong prefetched (batch B's s_loads issue
// before batch A's compute; the single lgkmcnt(0) lands after ~130cy of VALU).
// Steady-state loop has ZERO ds/flat ops besides the rare exec-masked push, so
// lgkmcnt counts only SMEM. Filter: g<G (3 fma + cmp), conservative by GMARGIN;
// FLUSH re-gathers from L2 and re-filters with exact reference rounding, so
// selection + tie semantics are identical to the previous passing kernel.
__global__ __launch_bounds__(NTHR, 4) void k_knn_fe(
    const float4* __restrict__ pk, const float4* __restrict__ prm,
    const float* __restrict__ feature, const float* __restrict__ wsM,
    const float* __restrict__ bs, float* __restrict__ out) {
  const int blk = blockIdx.x;
  const int b  = blk / BLOCKS_PER_B;
  const int n0 = (blk % BLOCKS_PER_B) * QPB;
  const int t = threadIdx.x;
  const int q = t & 63;
  const int j = __builtin_amdgcn_readfirstlane(t >> 6);  // wave-uniform partner id
  const int lbase = t * CAPP;                            // per-lane idx-buffer base
  const size_t bb = (size_t)b << 13;

  __shared__ unsigned tau[QPB];
  __shared__ float4 prmL[2 * HDIM];
  // poolF (32KB): merge d-rows [128][64] -> epilogue ws[128][64]
  // poolI (17.4KB): scan idx-buffer [512][17] -> merge id-rows [128][64]
  //                 -> epilogue feature tile (as float [64][64])
  __shared__ alignas(16) float poolF[128 * QPB];
  __shared__ alignas(16) unsigned short poolI[CAPP * NTHR];

  if (t < QPB) tau[t] = 0x7f800000u;  // +inf
  for (int i = t; i < 2 * HDIM; i += NTHR) prmL[i] = prm[i];

  const float4 qv = pk[bb + n0 + q];
  const float qx = qv.x, qy = qv.y, qz = qv.z, qs = qv.w;
  const float nx2 = -2.0f * qx, ny2 = -2.0f * qy, nz2 = -2.0f * qz;

  const float INF = __uint_as_float(0x7f800000u);
  float v[KNN]; int id[KNN];
  float vmax, gate, G;
  int cnt = 0;
  __syncthreads();

  const float4* pj = pk + bb + (size_t)j * CHUNK;
  const int jC = j * CHUNK;

  // warm start: first 16 candidates fill the list directly with exact d
  {
    float4 c[KNN];
#pragma unroll
    for (int e = 0; e < KNN; e++) c[e] = pj[e];
#pragma unroll
    for (int e = 0; e < KNN; e++) {
      float dot = fmaf(c[e].z, qz, fmaf(c[e].y, qy, __fmul_rn(c[e].x, qx)));
      v[e] = fmaf(-2.0f, dot, __fadd_rn(qs, c[e].w));  // == (qs+cw) - 2*dot exactly
      id[e] = jC + e;
    }
    MAX16(v, vmax);
    unsigned old = atomicMin(&tau[q], __float_as_uint(vmax));
    gate = fminf(vmax, __uint_as_float(old));
    G = __fadd_rn(__fsub_rn(gate, qs), GMARGIN);
  }

  // ping-pong software pipeline over 8-candidate wave-uniform batches
  {
    float4 ca[8], cb[8];
#pragma unroll
    for (int e = 0; e < 8; e++) ca[e] = pj[KNN + e];
    for (int u0 = KNN; u0 < CHUNK; u0 += 16) {
#pragma unroll
      for (int e = 0; e < 8; e++) cb[e] = pj[u0 + 8 + e];   // prefetch B
      PROC8(ca, u0);
#pragma unroll
      for (int e = 0; e < 8; e++) ca[e] = pj[u0 + 16 + e];  // prefetch A' (last: pad)
      PROC8(cb, u0 + 8);
    }
  }
  FLUSH();
  __syncthreads();

  // publish per-thread lists: rows j*16+i (ascending-m order across j)
#pragma unroll
  for (int i = 0; i < KNN; i++) {
    poolF[(j * KNN + i) * QPB + q] = v[i];
    poolI[(j * KNN + i) * QPB + q] = (unsigned short)id[i];
  }
  __syncthreads();

  float fv[KNN]; int fid[KNN]; float fm = INF;
  // stage A: wave j<4 merges partners (2j, 2j+1) -> rows (2j)*16
  if (j < 4) {
    const int l0 = (2 * j) * KNN, r1 = (2 * j + 1) * KNN;
#pragma unroll
    for (int i = 0; i < KNN; i++) {
      fv[i] = poolF[(l0 + i) * QPB + q];
      fid[i] = poolI[(l0 + i) * QPB + q];
    }
    MAX16(fv, fm);
    for (int s = 0; s < KNN; s++) {
      float d = poolF[(r1 + s) * QPB + q];
      if (d < fm) { int m_ = poolI[(r1 + s) * QPB + q]; INSERT16(fv, fid, fm, d, m_); }
    }
#pragma unroll
    for (int i = 0; i < KNN; i++) {
      poolF[(l0 + i) * QPB + q] = fv[i];
      poolI[(l0 + i) * QPB + q] = (unsigned short)fid[i];
    }
  }
  __syncthreads();
  // stage B: wave0: rows0+rows32 ; wave1: rows64+rows96 (ascending order kept)
  if (j < 2) {
    const int l0 = (4 * j) * KNN, r1 = (4 * j + 2) * KNN;
#pragma unroll
    for (int i = 0; i < KNN; i++) {
      fv[i] = poolF[(l0 + i) * QPB + q];
      fid[i] = poolI[(l0 + i) * QPB + q];
    }
    MAX16(fv, fm);
    for (int s = 0; s < KNN; s++) {
      float d = poolF[(r1 + s) * QPB + q];
      if (d < fm) { int m_ = poolI[(r1 + s) * QPB + q]; INSERT16(fv, fid, fm, d, m_); }
    }
#pragma unroll
    for (int i = 0; i < KNN; i++) {
      poolF[(l0 + i) * QPB + q] = fv[i];
      poolI[(l0 + i) * QPB + q] = (unsigned short)fid[i];
    }
  }
  __syncthreads();
  // stage C: wave0 merges rows0 + rows64 -> final ids in poolI rows 0..15
  if (j == 0) {
#pragma unroll
    for (int i = 0; i < KNN; i++) {
      fv[i] = poolF[i * QPB + q];
      fid[i] = poolI[i * QPB + q];
    }
    MAX16(fv, fm);
    for (int s = 0; s < KNN; s++) {
      float d = poolF[(4 * KNN + s) * QPB + q];
      if (d < fm) { int m_ = poolI[(4 * KNN + s) * QPB + q]; INSERT16(fv, fid, fm, d, m_); }
    }
#pragma unroll
    for (int i = 0; i < KNN; i++) poolI[i * QPB + q] = (unsigned short)fid[i];
  }
  __syncthreads();

  // gather neighbors (2 per wave-slot) into poolF rows 0..63
#pragma unroll
  for (int kk = 0; kk < 2; kk++) {
    int k = j * 2 + kk;
    int m = poolI[k * QPB + q];
    float4 c = pk[bb + m];
    float dx = __fsub_rn(c.x, qx), dy = __fsub_rn(c.y, qy), dz = __fsub_rn(c.z, qz);
    float dsq = __fadd_rn(__fadd_rn(__fmul_rn(dx, dx), __fmul_rn(dy, dy)),
                          __fmul_rn(dz, dz));
    poolF[k * QPB + q] = c.x;
    poolF[(KNN + k) * QPB + q] = c.y;
    poolF[(2 * KNN + k) * QPB + q] = c.z;
    poolF[(3 * KNN + k) * QPB + q] = dsq;
  }
  __syncthreads();

  float fo[8];
  {
    float nx[KNN], ny[KNN], nz[KNN], nd[KNN];
#pragma unroll
    for (int k = 0; k < KNN; k++) {
      nx[k] = poolF[k * QPB + q];
      ny[k] = poolF[(KNN + k) * QPB + q];
      nz[k] = poolF[(2 * KNN + k) * QPB + q];
      nd[k] = poolF[(3 * KNN + k) * QPB + q];
    }
#pragma unroll
    for (int oi = 0; oi < 8; oi++) {
      int o = j * 8 + oi;
      float4 pA = prmL[o], pB = prmL[HDIM + o];
      float basev = fmaf(qz, pA.z, fmaf(qy, pA.y, fmaf(qx, pA.x, pA.w)));
      float mx = -INF;
#pragma unroll
      for (int k = 0; k < KNN; k++) {
        float tv = fmaf(nz[k], pB.z,
                   fmaf(ny[k], pB.y,
                   fmaf(nx[k], pB.x, __fmul_rn(nd[k], pB.w))));
        mx = fmaxf(mx, tv);
      }
      fo[oi] = basev + mx;
    }
  }
  __syncthreads();  // pool free -> reuse for ws + feature tile

  // stage ws [128][64] into poolF (32 KB), feature tile [64][64] into poolI (16 KB)
  float* wsL = poolF;
  float* feL = (float*)poolI;
  for (int i = t; i < DOUT * DIN; i += NTHR) wsL[i] = wsM[i];
#pragma unroll
  for (int r = 0; r < 8; r++) {
    int c = j * 8 + r;
    feL[c * QPB + q] = feature[(size_t)(b * DIN + c) * N_ + n0 + q];
  }
  __syncthreads();

  // shortcut GEMM: wave j computes outputs o=j*8..j*8+7 and o+64 for its query q
  float acc[16];
#pragma unroll
  for (int oi = 0; oi < 16; oi++) acc[oi] = 0.f;
  for (int c4 = 0; c4 < DIN / 4; c4++) {
    float f0 = feL[(4 * c4 + 0) * QPB + q];
    float f1 = feL[(4 * c4 + 1) * QPB + q];
    float f2 = feL[(4 * c4 + 2) * QPB + q];
    float f3 = feL[(4 * c4 + 3) * QPB + q];
#pragma unroll
    for (int oi = 0; oi < 16; oi++) {
      int o = (oi < 8) ? (j * 8 + oi) : (64 + j * 8 + oi - 8);
      float4 w = ((const float4*)(wsL + o * DIN))[c4];  // wave-uniform broadcast
      acc[oi] = fmaf(w.x, f0, acc[oi]);
      acc[oi] = fmaf(w.y, f1, acc[oi]);
      acc[oi] = fmaf(w.z, f2, acc[oi]);
      acc[oi] = fmaf(w.w, f3, acc[oi]);
    }
  }
  float* ob = out + (size_t)b * DOUT * N_ + n0 + q;
#pragma unroll
  for (int oi = 0; oi < 16; oi++) {
    int o = (oi < 8) ? (j * 8 + oi) : (64 + j * 8 + oi - 8);
    ob[(size_t)o * N_] = acc[oi] + bs[o] + fo[oi & 7];
  }
}

extern "C" void kernel_launch(void* const* d_in, const int* in_sizes, int n_in,
                              void* d_out, int out_size, void* d_ws, size_t ws_size,
                              hipStream_t stream) {
  const float* xyz     = (const float*)d_in[0];
  const float* feature = (const float*)d_in[1];
  const float* w1 = (const float*)d_in[2];
  const float* b1 = (const float*)d_in[3];
  const float* w2 = (const float*)d_in[4];
  const float* b2 = (const float*)d_in[5];
  const float* w3 = (const float*)d_in[6];
  const float* b3 = (const float*)d_in[7];
  const float* wsM = (const float*)d_in[8];
  const float* bs  = (const float*)d_in[9];
  float* out = (float*)d_out;

  // workspace: [0,8KB) prm, [8KB, 8KB+512KB) packed pk, +128B prefetch pad
  float4* prm = (float4*)d_ws;
  float4* pkB = (float4*)((char*)d_ws + 8192);

  hipLaunchKernelGGL(k_prep, dim3(128), dim3(256), 0, stream,
                     xyz, w1, b1, w2, b2, w3, b3, pkB, prm);
  hipLaunchKernelGGL(k_knn_fe, dim3(B_ * BLOCKS_PER_B), dim3(NTHR), 0, stream,
                     pkB, prm, feature, wsM, bs, out);
}